// Round 14
// baseline (247.708 us; speedup 1.0000x reference)
//
#include <hip/hip_runtime.h>
#include <hip/hip_bf16.h>

// B=4, M=2048, D=1024, H=16, K=V=64
#define B_  4
#define M_  2048
#define D_  1024
#define H_  16

typedef __attribute__((ext_vector_type(8)))  short bf16x8;
typedef __attribute__((ext_vector_type(4)))  float f32x4;
typedef __attribute__((ext_vector_type(16))) float f32x16;
typedef __attribute__((ext_vector_type(4)))  unsigned short u16x4;
typedef __attribute__((ext_vector_type(2)))  unsigned int uint2v;

#define MFMA16(a, b, c) __builtin_amdgcn_mfma_f32_16x16x32_bf16((a), (b), (c), 0, 0, 0)
#define MFMA32(a, b, c) __builtin_amdgcn_mfma_f32_32x32x16_bf16((a), (b), (c), 0, 0, 0)

// Q pre-scale: 1/sqrt(64) * log2(e)  (softmax done in exp2 domain)
#define QSCALE 0.18033688011112042f

__device__ __forceinline__ unsigned short f2b(float f) {
  union { float f; unsigned u; } v; v.f = f;
  unsigned r = v.u + 0x7FFF + ((v.u >> 16) & 1);   // RNE
  return (unsigned short)(r >> 16);
}

__device__ __forceinline__ unsigned cvtpk(float lo, float hi) {
  unsigned r;
  asm("v_cvt_pk_bf16_f32 %0, %1, %2" : "=v"(r) : "v"(lo), "v"(hi));
  return r;
}

// GEMM-tile swizzle: 128B rows, XOR 16B-slot bits 4-6 with row low bits.
__device__ __forceinline__ int swzb(int byte) {
  return byte ^ (((byte >> 7) & 7) << 4);
}

#define GLOAD16(gsrc, ldst)                                                     \
  __builtin_amdgcn_global_load_lds(                                             \
      (const __attribute__((address_space(1))) void*)(gsrc),                    \
      (__attribute__((address_space(3))) void*)(ldst), 16, 0, 0)

// ---------------------------------------------------------------------------
// Fused conversions: one launch. blocks [0,4096): x -> bf16;
// [4096,7168): P_qkv -> Wt[n][d]; [7168,8192): P_o -> Wo[d][hv].
// ---------------------------------------------------------------------------
__global__ __launch_bounds__(256) void convert_all_kernel(
    const float* __restrict__ x,  const float* __restrict__ Pq,
    const float* __restrict__ Pk, const float* __restrict__ Pv,
    const float* __restrict__ Po,
    short* __restrict__ xb, short* __restrict__ Wt, short* __restrict__ Wo) {
  const int bid = blockIdx.x;
  if (bid < 4096) {
    const size_t i = ((size_t)bid * 256 + threadIdx.x) * 8;
    float4 a = *(const float4*)(x + i);
    float4 b = *(const float4*)(x + i + 4);
    bf16x8 o;
    o[0] = (short)f2b(a.x); o[1] = (short)f2b(a.y); o[2] = (short)f2b(a.z); o[3] = (short)f2b(a.w);
    o[4] = (short)f2b(b.x); o[5] = (short)f2b(b.y); o[6] = (short)f2b(b.z); o[7] = (short)f2b(b.w);
    *(bf16x8*)(xb + i) = o;
  } else if (bid < 7168) {
    const int idx = (bid - 4096) * 256 + threadIdx.x;   // n*256 + d/4
    const int n = idx >> 8, d0 = (idx & 255) * 4;
    const int which = n >> 10, h = (n >> 6) & 15, kc = n & 63;
    const float* P = (which == 0) ? Pq : (which == 1) ? Pk : Pv;
    const float* p = P + ((size_t)h * D_ + d0) * 64 + kc;
    u16x4 o;
    o[0] = f2b(p[0]); o[1] = f2b(p[64]); o[2] = f2b(p[128]); o[3] = f2b(p[192]);
    *(u16x4*)(Wt + (size_t)n * D_ + d0) = o;
  } else {
    const int idx = (bid - 7168) * 256 + threadIdx.x;   // d*256 + hv/4
    const int d = idx >> 8, hv0 = (idx & 255) * 4;
    const int h = hv0 >> 6, v = hv0 & 63;
    float4 a = *(const float4*)(Po + ((size_t)h * D_ + d) * 64 + v);
    u16x4 o;
    o[0] = f2b(a.x); o[1] = f2b(a.y); o[2] = f2b(a.z); o[3] = f2b(a.w);
    *(u16x4*)(Wo + (size_t)d * 1024 + hv0) = o;
  }
}

// ---------------------------------------------------------------------------
// Single-buffered m97-style GEMM body (r10, proven): 128x128, BK=64,
// 256 threads, 32 KB LDS -> ~4-5 co-resident blocks/CU (m114 overlap).
// ---------------------------------------------------------------------------
__device__ __forceinline__ void gemm_body_sb(
    const char* __restrict__ Agc, const char* __restrict__ Bgc,
    short* As, short* Bs, int t, int w, int lane,
    f32x4 (&acc)[4][4])
{
  const int wr = (w >> 1) * 64, wc = (w & 1) * 64;
  const int lrow = lane & 15, lgrp = lane >> 4;

  for (int kt = 0; kt < 16; ++kt) {
    __syncthreads();                         // all waves done reading LDS
    const int d2 = kt * 128;                 // K-offset in bytes
#pragma unroll
    for (int i = 0; i < 4; ++i) {            // 128 rows x 128B each side
      const int L = i * 4096 + t * 16;
      const int row = L >> 7;
      const int cs = (L & 127) ^ ((row & 7) << 4);
      GLOAD16(Agc + (size_t)row * 2048 + d2 + cs, (char*)As + L);
      GLOAD16(Bgc + (size_t)row * 2048 + d2 + cs, (char*)Bs + L);
    }
    __syncthreads();                         // drains vmcnt -> tile visible
#pragma unroll
    for (int ks = 0; ks < 2; ++ks) {
      bf16x8 a[4], b[4];
      const int cb = ks * 64 + lgrp * 16;
#pragma unroll
      for (int f = 0; f < 4; ++f) {
        a[f] = *(const bf16x8*)((const char*)As + swzb((wr + f * 16 + lrow) * 128 + cb));
        b[f] = *(const bf16x8*)((const char*)Bs + swzb((wc + f * 16 + lrow) * 128 + cb));
      }
      __builtin_amdgcn_s_setprio(1);
#pragma unroll
      for (int mf = 0; mf < 4; ++mf)
#pragma unroll
        for (int nf = 0; nf < 4; ++nf)
          acc[mf][nf] = MFMA16(a[mf], b[nf], acc[mf][nf]);
      __builtin_amdgcn_s_setprio(0);
    }
  }
}

// ---------------------------------------------------------------------------
// QKV projection GEMM (r10, proven)
// ---------------------------------------------------------------------------
__global__ __launch_bounds__(256) void qkv_gemm_kernel(
    const short* __restrict__ xb, const short* __restrict__ Wt,
    short* __restrict__ Qw, short* __restrict__ Kw, short* __restrict__ Vt) {
  __shared__ short As[8192];
  __shared__ short Bs[8192];
  const int bid = blockIdx.x;                 // 1536
  const int xcd = bid & 7, slot = bid >> 3;   // slot 0..191
  const int m0 = (xcd * 8 + (slot & 7)) * 128;
  const int n0 = (slot >> 3) * 128;
  const int t = threadIdx.x, lane = t & 63, w = t >> 6;

  f32x4 acc[4][4] = {};
  gemm_body_sb((const char*)xb + (size_t)m0 * 2048,
               (const char*)Wt + (size_t)n0 * 2048,
               As, Bs, t, w, lane, acc);

  const int wr = (w >> 1) * 64, wc = (w & 1) * 64;
  const int lrow = lane & 15, lgrp = lane >> 4;
#pragma unroll
  for (int nf = 0; nf < 4; ++nf) {
    const int n = n0 + wc + nf * 16 + lrow;
    const int which = n >> 10, h = (n >> 6) & 15, kc = n & 63;
#pragma unroll
    for (int mf = 0; mf < 4; ++mf) {
      const int row0 = m0 + wr + mf * 16 + lgrp * 4;
      const int b = row0 >> 11, mm = row0 & 2047;
      const int bh = b * 16 + h;
      if (which == 2) {
        u16x4 o;
        o[0] = f2b(acc[mf][nf][0]); o[1] = f2b(acc[mf][nf][1]);
        o[2] = f2b(acc[mf][nf][2]); o[3] = f2b(acc[mf][nf][3]);
        *(u16x4*)(Vt + ((size_t)bh * 64 + kc) * M_ + mm) = o;
      } else {
        short* outp = (which == 0 ? Qw : Kw) + ((size_t)bh * M_ + mm) * 64 + kc;
        const float scale = (which == 0) ? QSCALE : 1.0f;
#pragma unroll
        for (int r = 0; r < 4; ++r)
          outp[(size_t)r * 64] = (short)f2b(acc[mf][nf][r] * scale);
      }
    }
  }
}

// ---------------------------------------------------------------------------
// Output projection (r10, proven)
// ---------------------------------------------------------------------------
__global__ __launch_bounds__(256) void out_gemm_kernel(
    const short* __restrict__ O2, const short* __restrict__ Wo,
    float* __restrict__ y) {
  __shared__ short As[8192];
  __shared__ short Bs[8192];
  const int bid = blockIdx.x;                 // 512
  const int xcd = bid & 7, slot = bid >> 3;   // slot 0..63
  const int m0 = (xcd * 8 + (slot & 7)) * 128;
  const int n0 = (slot >> 3) * 128;
  const int t = threadIdx.x, lane = t & 63, w = t >> 6;

  f32x4 acc[4][4] = {};
  gemm_body_sb((const char*)O2 + (size_t)m0 * 2048,
               (const char*)Wo + (size_t)n0 * 2048,
               As, Bs, t, w, lane, acc);

  const int wr = (w >> 1) * 64, wc = (w & 1) * 64;
  const int lrow = lane & 15, lgrp = lane >> 4;
#pragma unroll
  for (int mf = 0; mf < 4; ++mf)
#pragma unroll
    for (int nf = 0; nf < 4; ++nf) {
      const int n = n0 + wc + nf * 16 + lrow;
      const int row0 = m0 + wr + mf * 16 + lgrp * 4;
#pragma unroll
      for (int r = 0; r < 4; ++r)
        y[(size_t)(row0 + r) * 1024 + n] = acc[mf][nf][r];
    }
}

// ---------------------------------------------------------------------------
// Attention softmax (r13 form: max3-shaped row-max, T13 defer, T12 cvtpk)
// ---------------------------------------------------------------------------
__device__ __forceinline__ void softmax_chunk(
    f32x16& s0, f32x16& s1, f32x16& o0, f32x16& o1,
    float& mrun, float& lrun, bf16x8 (&pf)[4])
{
  // row max over 32 values: triples fuse to v_max3_f32
  float a[8];
#pragma unroll
  for (int r = 0; r < 8; ++r)
    a[r] = fmaxf(fmaxf(fmaxf(s0[r], s0[r + 8]), s1[r]), s1[r + 8]);
  float b0 = fmaxf(fmaxf(a[0], a[1]), a[2]);
  float b1 = fmaxf(fmaxf(a[3], a[4]), a[5]);
  float b2 = fmaxf(fmaxf(a[6], a[7]), b0);
  float tmax = fmaxf(b1, b2);
  uint2v pm = __builtin_amdgcn_permlane32_swap(
      __float_as_uint(tmax), __float_as_uint(tmax), false, false);
  const float mtile = fmaxf(__uint_as_float(pm[0]), __uint_as_float(pm[1]));

  // T13 defer-max: skip rescale while max grows < 8 (exp2 domain; P <= 256)
  if (!__all(mtile <= mrun + 8.0f)) {
    const float mnew = fmaxf(mrun, mtile);
    const float alpha = __builtin_amdgcn_exp2f(mrun - mnew);
    mrun = mnew;
    lrun *= alpha;
    o0 *= alpha;
    o1 *= alpha;
  }
#pragma unroll
  for (int r = 0; r < 16; ++r) {
    s0[r] = __builtin_amdgcn_exp2f(s0[r] - mrun);
    s1[r] = __builtin_amdgcn_exp2f(s1[r] - mrun);
  }
  // P -> bf16 PV B-operand frags, fully in-register (T12)
#pragma unroll
  for (int c = 0; c < 4; ++c) {
    const f32x16& sv = (c < 2) ? s0 : s1;    // c is unroll-constant
    const int rb = (c & 1) * 8;
    unsigned a0 = cvtpk(sv[rb + 0], sv[rb + 1]);
    unsigned a1 = cvtpk(sv[rb + 2], sv[rb + 3]);
    unsigned b0_ = cvtpk(sv[rb + 4], sv[rb + 5]);
    unsigned b1_ = cvtpk(sv[rb + 6], sv[rb + 7]);
    uint2v t0 = __builtin_amdgcn_permlane32_swap(a0, b0_, false, false);
    uint2v t1 = __builtin_amdgcn_permlane32_swap(a1, b1_, false, false);
    union { unsigned u[4]; bf16x8 v; } pk;
    pk.u[0] = t0[0]; pk.u[1] = t1[0]; pk.u[2] = t0[1]; pk.u[3] = t1[1];
    pf[c] = pk.v;
  }
}

// ---------------------------------------------------------------------------
// Flash attention, LDS-free (guide common-mistake #7 / m169): per-XCD K/V
// working set = 8 bh x 512 KB = 4 MB = one XCD's L2, pinned by bh%8 == XCD.
// K/V MFMA fragments are read DIRECTLY from global (L1/L2); no staging, no
// barriers — waves fully independent, each loops only to its own causal
// bound. 1024 blocks = 16 chunks (heavy-first) x 64 bh; 4 waves x 32 q-rows.
// ---------------------------------------------------------------------------
__global__ __launch_bounds__(256) void attn_kernel(
    const short* __restrict__ Qw, const short* __restrict__ Kw,
    const short* __restrict__ Vt, short* __restrict__ O2) {
  const int bid = blockIdx.x;                 // 1024 blocks
  const int chunk = 15 - (bid >> 6);          // heavy-first
  const int bh = bid & 63;                    // bh%8 == dispatch XCD
  const int q0 = chunk * 128;

  const int t = threadIdx.x, lane = t & 63, w = t >> 6;
  const int l31 = lane & 31, hi = lane >> 5;
  const int qw0 = q0 + w * 32;                // this wave's 32 q-rows
  const int qabs = qw0 + l31;

  bf16x8 qfrag[4];
#pragma unroll
  for (int kc = 0; kc < 4; ++kc)
    qfrag[kc] = *(const bf16x8*)(Qw + ((size_t)bh * M_ + qabs) * 64 + kc * 16 + hi * 8);

  f32x16 o0 = {}, o1 = {};
  float mrun = -3.0e38f, lrun = 0.f;

  const char* Kg = (const char*)Kw + (size_t)bh * M_ * 128;
  const char* Vg = (const char*)Vt + (size_t)bh * 64 * (M_ * 2);

  bf16x8 ones;
#pragma unroll
  for (int e = 0; e < 8; ++e) ones[e] = (short)0x3F80;   // bf16 1.0

  const int jend = qw0 + 32;                  // keys needed: <= qw0+31
  for (int j0 = 0; j0 < jend; j0 += 64) {
    // ---- S^T = K . Q^T : K frags direct from L1/L2 ----
    f32x16 s0 = {}, s1 = {};
    __builtin_amdgcn_s_setprio(1);
#pragma unroll
    for (int kc = 0; kc < 4; ++kc) {
      bf16x8 kf0 = *(const bf16x8*)(Kg + (size_t)(j0 + l31) * 128 + kc * 32 + hi * 16);
      s0 = MFMA32(kf0, qfrag[kc], s0);
      bf16x8 kf1 = *(const bf16x8*)(Kg + (size_t)(j0 + 32 + l31) * 128 + kc * 32 + hi * 16);
      s1 = MFMA32(kf1, qfrag[kc], s1);
    }
    __builtin_amdgcn_s_setprio(0);

    // ---- causal mask (diagonal tiles only) ----
    if (j0 + 64 > qw0) {
#pragma unroll
      for (int r = 0; r < 16; ++r) {
        const int k0 = j0 + (r & 3) + 8 * (r >> 2) + 4 * hi;
        if (k0 > qabs)      s0[r] = -3.0e38f;
        if (k0 + 32 > qabs) s1[r] = -3.0e38f;
      }
    }

    // ---- online softmax + P->bf16 frags ----
    bf16x8 pf[4];
    softmax_chunk(s0, s1, o0, o1, mrun, lrun, pf);

    // ---- O^T += V^T . P : V frags direct from L1/L2 ([v][m] layout) ----
    f32x16 lacc = {};
    __builtin_amdgcn_s_setprio(1);
#pragma unroll
    for (int c = 0; c < 4; ++c) {
      bf16x8 vf0 = *(const bf16x8*)(Vg + (size_t)l31 * (M_ * 2) + (size_t)j0 * 2 + c * 32 + hi * 16);
      o0 = MFMA32(vf0, pf[c], o0);
      bf16x8 vf1 = *(const bf16x8*)(Vg + (size_t)(32 + l31) * (M_ * 2) + (size_t)j0 * 2 + c * 32 + hi * 16);
      o1 = MFMA32(vf1, pf[c], o1);
      lacc = MFMA32(ones, pf[c], lacc);      // rowsum of P on MFMA pipe
    }
    __builtin_amdgcn_s_setprio(0);
    lrun += lacc[0];
  }

  // ---- epilogue: O2[b][m=qabs][h*64 + v] = O^T / l ----
  const int b = bh >> 4, h = bh & 15;
  const float inv = 1.0f / lrun;
  short* orow = O2 + ((size_t)b * M_ + qabs) * 1024 + h * 64;
#pragma unroll
  for (int vb = 0; vb < 2; ++vb) {
    const f32x16& o = vb ? o1 : o0;
#pragma unroll
    for (int g = 0; g < 4; ++g) {
      const int vbase = vb * 32 + 8 * g + 4 * hi;
      u16x4 pkt;
      pkt[0] = f2b(o[g * 4 + 0] * inv);
      pkt[1] = f2b(o[g * 4 + 1] * inv);
      pkt[2] = f2b(o[g * 4 + 2] * inv);
      pkt[3] = f2b(o[g * 4 + 3] * inv);
      *(u16x4*)(orow + vbase) = pkt;
    }
  }
}

// ---------------------------------------------------------------------------
extern "C" void kernel_launch(void* const* d_in, const int* in_sizes, int n_in,
                              void* d_out, int out_size, void* d_ws, size_t ws_size,
                              hipStream_t stream) {
  const float* x  = (const float*)d_in[0];
  const float* Pq = (const float*)d_in[1];
  const float* Pk = (const float*)d_in[2];
  const float* Pv = (const float*)d_in[3];
  const float* Po = (const float*)d_in[4];
  float* y = (float*)d_out;

  short* ws = (short*)d_ws;
  const size_t NX = (size_t)B_ * M_ * D_;        // 8,388,608
  short* xb  = ws;                 ws += NX;
  short* Wt  = ws;                 ws += (size_t)3072 * 1024;
  short* Wo  = ws;                 ws += (size_t)1024 * 1024;
  short* Qw  = ws;                 ws += NX;
  short* Kw  = ws;                 ws += NX;
  short* Vt  = ws;                 ws += NX;
  short* O2  = ws;                 ws += NX;

  convert_all_kernel<<<8192, 256, 0, stream>>>(x, Pq, Pk, Pv, Po, xb, Wt, Wo);
  qkv_gemm_kernel   <<<1536, 256, 0, stream>>>(xb, Wt, Qw, Kw, Vt);
  attn_kernel       <<<1024, 256, 0, stream>>>(Qw, Kw, Vt, O2);
  out_gemm_kernel   <<<512,  256, 0, stream>>>(O2, Wo, y);
}

// Round 15
// 176.599 us; speedup vs baseline: 1.4027x; 1.4027x over previous
//
#include <hip/hip_runtime.h>
#include <hip/hip_bf16.h>

// B=4, M=2048, D=1024, H=16, K=V=64
#define B_  4
#define M_  2048
#define D_  1024
#define H_  16

typedef __attribute__((ext_vector_type(8)))  short bf16x8;
typedef __attribute__((ext_vector_type(4)))  float f32x4;
typedef __attribute__((ext_vector_type(16))) float f32x16;
typedef __attribute__((ext_vector_type(4)))  unsigned short u16x4;
typedef __attribute__((ext_vector_type(2)))  unsigned int uint2v;

#define MFMA16(a, b, c) __builtin_amdgcn_mfma_f32_16x16x32_bf16((a), (b), (c), 0, 0, 0)
#define MFMA32(a, b, c) __builtin_amdgcn_mfma_f32_32x32x16_bf16((a), (b), (c), 0, 0, 0)

// Q pre-scale: 1/sqrt(64) * log2(e)  (softmax done in exp2 domain)
#define QSCALE 0.18033688011112042f

__device__ __forceinline__ unsigned short f2b(float f) {
  union { float f; unsigned u; } v; v.f = f;
  unsigned r = v.u + 0x7FFF + ((v.u >> 16) & 1);   // RNE
  return (unsigned short)(r >> 16);
}

__device__ __forceinline__ unsigned cvtpk(float lo, float hi) {
  unsigned r;
  asm("v_cvt_pk_bf16_f32 %0, %1, %2" : "=v"(r) : "v"(lo), "v"(hi));
  return r;
}

// GEMM-tile swizzle: 128B rows, XOR 16B-slot bits 4-6 with row low bits.
__device__ __forceinline__ int swzb(int byte) {
  return byte ^ (((byte >> 7) & 7) << 4);
}

// Attention swizzle: 256B macro-rows.
#define SWZ256(L) ((L) ^ ((((L) >> 8) & 15) << 4))

#define GLOAD16(gsrc, ldst)                                                     \
  __builtin_amdgcn_global_load_lds(                                             \
      (const __attribute__((address_space(1))) void*)(gsrc),                    \
      (__attribute__((address_space(3))) void*)(ldst), 16, 0, 0)

// ---------------------------------------------------------------------------
// Fused conversions: one launch. blocks [0,4096): x -> bf16;
// [4096,7168): P_qkv -> Wt[n][d]; [7168,8192): P_o -> Wo[d][hv].
// ---------------------------------------------------------------------------
__global__ __launch_bounds__(256) void convert_all_kernel(
    const float* __restrict__ x,  const float* __restrict__ Pq,
    const float* __restrict__ Pk, const float* __restrict__ Pv,
    const float* __restrict__ Po,
    short* __restrict__ xb, short* __restrict__ Wt, short* __restrict__ Wo) {
  const int bid = blockIdx.x;
  if (bid < 4096) {
    const size_t i = ((size_t)bid * 256 + threadIdx.x) * 8;
    float4 a = *(const float4*)(x + i);
    float4 b = *(const float4*)(x + i + 4);
    bf16x8 o;
    o[0] = (short)f2b(a.x); o[1] = (short)f2b(a.y); o[2] = (short)f2b(a.z); o[3] = (short)f2b(a.w);
    o[4] = (short)f2b(b.x); o[5] = (short)f2b(b.y); o[6] = (short)f2b(b.z); o[7] = (short)f2b(b.w);
    *(bf16x8*)(xb + i) = o;
  } else if (bid < 7168) {
    const int idx = (bid - 4096) * 256 + threadIdx.x;   // n*256 + d/4
    const int n = idx >> 8, d0 = (idx & 255) * 4;
    const int which = n >> 10, h = (n >> 6) & 15, kc = n & 63;
    const float* P = (which == 0) ? Pq : (which == 1) ? Pk : Pv;
    const float* p = P + ((size_t)h * D_ + d0) * 64 + kc;
    u16x4 o;
    o[0] = f2b(p[0]); o[1] = f2b(p[64]); o[2] = f2b(p[128]); o[3] = f2b(p[192]);
    *(u16x4*)(Wt + (size_t)n * D_ + d0) = o;
  } else {
    const int idx = (bid - 7168) * 256 + threadIdx.x;   // d*256 + hv/4
    const int d = idx >> 8, hv0 = (idx & 255) * 4;
    const int h = hv0 >> 6, v = hv0 & 63;
    float4 a = *(const float4*)(Po + ((size_t)h * D_ + d) * 64 + v);
    u16x4 o;
    o[0] = f2b(a.x); o[1] = f2b(a.y); o[2] = f2b(a.z); o[3] = f2b(a.w);
    *(u16x4*)(Wo + (size_t)d * 1024 + hv0) = o;
  }
}

// ---------------------------------------------------------------------------
// Single-buffered m97-style GEMM body (proven): 128x128, BK=64,
// 256 threads, 32 KB LDS -> ~4-5 co-resident blocks/CU (m114 overlap).
// ---------------------------------------------------------------------------
__device__ __forceinline__ void gemm_body_sb(
    const char* __restrict__ Agc, const char* __restrict__ Bgc,
    short* As, short* Bs, int t, int w, int lane,
    f32x4 (&acc)[4][4])
{
  const int wr = (w >> 1) * 64, wc = (w & 1) * 64;
  const int lrow = lane & 15, lgrp = lane >> 4;

  for (int kt = 0; kt < 16; ++kt) {
    __syncthreads();                         // all waves done reading LDS
    const int d2 = kt * 128;                 // K-offset in bytes
#pragma unroll
    for (int i = 0; i < 4; ++i) {            // 128 rows x 128B each side
      const int L = i * 4096 + t * 16;
      const int row = L >> 7;
      const int cs = (L & 127) ^ ((row & 7) << 4);
      GLOAD16(Agc + (size_t)row * 2048 + d2 + cs, (char*)As + L);
      GLOAD16(Bgc + (size_t)row * 2048 + d2 + cs, (char*)Bs + L);
    }
    __syncthreads();                         // drains vmcnt -> tile visible
#pragma unroll
    for (int ks = 0; ks < 2; ++ks) {
      bf16x8 a[4], b[4];
      const int cb = ks * 64 + lgrp * 16;
#pragma unroll
      for (int f = 0; f < 4; ++f) {
        a[f] = *(const bf16x8*)((const char*)As + swzb((wr + f * 16 + lrow) * 128 + cb));
        b[f] = *(const bf16x8*)((const char*)Bs + swzb((wc + f * 16 + lrow) * 128 + cb));
      }
      __builtin_amdgcn_s_setprio(1);
#pragma unroll
      for (int mf = 0; mf < 4; ++mf)
#pragma unroll
        for (int nf = 0; nf < 4; ++nf)
          acc[mf][nf] = MFMA16(a[mf], b[nf], acc[mf][nf]);
      __builtin_amdgcn_s_setprio(0);
    }
  }
}

// ---------------------------------------------------------------------------
// QKV projection GEMM (proven)
// ---------------------------------------------------------------------------
__global__ __launch_bounds__(256) void qkv_gemm_kernel(
    const short* __restrict__ xb, const short* __restrict__ Wt,
    short* __restrict__ Qw, short* __restrict__ Kw, short* __restrict__ Vt) {
  __shared__ short As[8192];
  __shared__ short Bs[8192];
  const int bid = blockIdx.x;                 // 1536
  const int xcd = bid & 7, slot = bid >> 3;   // slot 0..191
  const int m0 = (xcd * 8 + (slot & 7)) * 128;
  const int n0 = (slot >> 3) * 128;
  const int t = threadIdx.x, lane = t & 63, w = t >> 6;

  f32x4 acc[4][4] = {};
  gemm_body_sb((const char*)xb + (size_t)m0 * 2048,
               (const char*)Wt + (size_t)n0 * 2048,
               As, Bs, t, w, lane, acc);

  const int wr = (w >> 1) * 64, wc = (w & 1) * 64;
  const int lrow = lane & 15, lgrp = lane >> 4;
#pragma unroll
  for (int nf = 0; nf < 4; ++nf) {
    const int n = n0 + wc + nf * 16 + lrow;
    const int which = n >> 10, h = (n >> 6) & 15, kc = n & 63;
#pragma unroll
    for (int mf = 0; mf < 4; ++mf) {
      const int row0 = m0 + wr + mf * 16 + lgrp * 4;
      const int b = row0 >> 11, mm = row0 & 2047;
      const int bh = b * 16 + h;
      if (which == 2) {
        u16x4 o;
        o[0] = f2b(acc[mf][nf][0]); o[1] = f2b(acc[mf][nf][1]);
        o[2] = f2b(acc[mf][nf][2]); o[3] = f2b(acc[mf][nf][3]);
        *(u16x4*)(Vt + ((size_t)bh * 64 + kc) * M_ + mm) = o;
      } else {
        short* outp = (which == 0 ? Qw : Kw) + ((size_t)bh * M_ + mm) * 64 + kc;
        const float scale = (which == 0) ? QSCALE : 1.0f;
#pragma unroll
        for (int r = 0; r < 4; ++r)
          outp[(size_t)r * 64] = (short)f2b(acc[mf][nf][r] * scale);
      }
    }
  }
}

// ---------------------------------------------------------------------------
// Output projection (proven)
// ---------------------------------------------------------------------------
__global__ __launch_bounds__(256) void out_gemm_kernel(
    const short* __restrict__ O2, const short* __restrict__ Wo,
    float* __restrict__ y) {
  __shared__ short As[8192];
  __shared__ short Bs[8192];
  const int bid = blockIdx.x;                 // 512
  const int xcd = bid & 7, slot = bid >> 3;   // slot 0..63
  const int m0 = (xcd * 8 + (slot & 7)) * 128;
  const int n0 = (slot >> 3) * 128;
  const int t = threadIdx.x, lane = t & 63, w = t >> 6;

  f32x4 acc[4][4] = {};
  gemm_body_sb((const char*)O2 + (size_t)m0 * 2048,
               (const char*)Wo + (size_t)n0 * 2048,
               As, Bs, t, w, lane, acc);

  const int wr = (w >> 1) * 64, wc = (w & 1) * 64;
  const int lrow = lane & 15, lgrp = lane >> 4;
#pragma unroll
  for (int mf = 0; mf < 4; ++mf)
#pragma unroll
    for (int nf = 0; nf < 4; ++nf) {
      const int n = n0 + wc + nf * 16 + lrow;
      const int row0 = m0 + wr + mf * 16 + lgrp * 4;
#pragma unroll
      for (int r = 0; r < 4; ++r)
        y[(size_t)(row0 + r) * 1024 + n] = acc[mf][nf][r];
    }
}

// ---------------------------------------------------------------------------
// Attention softmax (max3-shaped row-max, T13 defer, T12 cvtpk+permlane)
// ---------------------------------------------------------------------------
__device__ __forceinline__ void softmax_chunk(
    f32x16& s0, f32x16& s1, f32x16& o0, f32x16& o1,
    float& mrun, float& lrun, bf16x8 (&pf)[4])
{
  // row max over 32 values: triples fuse to v_max3_f32
  float a[8];
#pragma unroll
  for (int r = 0; r < 8; ++r)
    a[r] = fmaxf(fmaxf(fmaxf(s0[r], s0[r + 8]), s1[r]), s1[r + 8]);
  float b0 = fmaxf(fmaxf(a[0], a[1]), a[2]);
  float b1 = fmaxf(fmaxf(a[3], a[4]), a[5]);
  float b2 = fmaxf(fmaxf(a[6], a[7]), b0);
  float tmax = fmaxf(b1, b2);
  uint2v pm = __builtin_amdgcn_permlane32_swap(
      __float_as_uint(tmax), __float_as_uint(tmax), false, false);
  const float mtile = fmaxf(__uint_as_float(pm[0]), __uint_as_float(pm[1]));

  // T13 defer-max: skip rescale while max grows < 8 (exp2 domain; P <= 256)
  if (!__all(mtile <= mrun + 8.0f)) {
    const float mnew = fmaxf(mrun, mtile);
    const float alpha = __builtin_amdgcn_exp2f(mrun - mnew);
    mrun = mnew;
    lrun *= alpha;
    o0 *= alpha;
    o1 *= alpha;
  }
#pragma unroll
  for (int r = 0; r < 16; ++r) {
    s0[r] = __builtin_amdgcn_exp2f(s0[r] - mrun);
    s1[r] = __builtin_amdgcn_exp2f(s1[r] - mrun);
  }
  // P -> bf16 PV B-operand frags, fully in-register (T12)
#pragma unroll
  for (int c = 0; c < 4; ++c) {
    const f32x16& sv = (c < 2) ? s0 : s1;    // c is unroll-constant
    const int rb = (c & 1) * 8;
    unsigned a0 = cvtpk(sv[rb + 0], sv[rb + 1]);
    unsigned a1 = cvtpk(sv[rb + 2], sv[rb + 3]);
    unsigned b0_ = cvtpk(sv[rb + 4], sv[rb + 5]);
    unsigned b1_ = cvtpk(sv[rb + 6], sv[rb + 7]);
    uint2v t0 = __builtin_amdgcn_permlane32_swap(a0, b0_, false, false);
    uint2v t1 = __builtin_amdgcn_permlane32_swap(a1, b1_, false, false);
    union { unsigned u[4]; bf16x8 v; } pk;
    pk.u[0] = t0[0]; pk.u[1] = t1[0]; pk.u[2] = t0[1]; pk.u[3] = t1[1];
    pf[c] = pk.v;
  }
}

// ---------------------------------------------------------------------------
// Flash attention (proven): 1024 blocks = 16 chunks (heavy-first) x
// 64 bh; dbuf LDS + counted vmcnt(4); VGPR ~92 -> 5 blocks/CU.
// ---------------------------------------------------------------------------
__global__ __launch_bounds__(256) void attn_kernel(
    const short* __restrict__ Qw, const short* __restrict__ Kw,
    const short* __restrict__ Vt, short* __restrict__ O2) {
  __shared__ short Ks[2][64 * 64];
  __shared__ short Vs[2][64 * 64];

  const int bid = blockIdx.x;                 // 1024 blocks
  const int chunk = 15 - (bid >> 6);          // heavy-first
  const int bh = bid & 63;                    // bh%8 == dispatch XCD
  const int q0 = chunk * 128;

  const int t = threadIdx.x, lane = t & 63, w = t >> 6;
  const int l31 = lane & 31, hi = lane >> 5;
  const int qw0 = q0 + w * 32;
  const int qabs = qw0 + l31;

  bf16x8 qfrag[4];
#pragma unroll
  for (int kc = 0; kc < 4; ++kc)
    qfrag[kc] = *(const bf16x8*)(Qw + ((size_t)bh * M_ + qabs) * 64 + kc * 16 + hi * 8);

  f32x16 o0 = {}, o1 = {};
  float mrun = -3.0e38f, lrun = 0.f;

  const char* Kg = (const char*)Kw + (size_t)bh * M_ * 128;
  const char* Vg = (const char*)Vt + (size_t)bh * 64 * M_ * 2;

  auto stage = [&](int bi, int j0_) {
#pragma unroll
    for (int i = 0; i < 2; ++i) {
      const int L  = i * 4096 + t * 16;
      const int Ls = SWZ256(L);
      const int row = Ls >> 7, col = Ls & 127;
      GLOAD16(Kg + (size_t)(j0_ + row) * 128 + col, (char*)Ks[bi] + i * 4096 + w * 1024);
      GLOAD16(Vg + (size_t)row * (M_ * 2) + (size_t)j0_ * 2 + col, (char*)Vs[bi] + i * 4096 + w * 1024);
    }
  };

  const int nt = (q0 + 128) >> 6;
  stage(0, 0);

  bf16x8 ones;
#pragma unroll
  for (int e = 0; e < 8; ++e) ones[e] = (short)0x3F80;

  for (int tt = 0; tt < nt; ++tt) {
    const int j0 = tt << 6;
    const int cur = tt & 1;
    __builtin_amdgcn_s_barrier();
    if (tt + 1 < nt) {
      stage(cur ^ 1, j0 + 64);
      asm volatile("s_waitcnt vmcnt(4)" ::: "memory");
    } else {
      asm volatile("s_waitcnt vmcnt(0)" ::: "memory");
    }
    __builtin_amdgcn_s_barrier();
    if (j0 >= qw0 + 32) continue;

    const char* Kc = (const char*)Ks[cur];
    const char* Vc = (const char*)Vs[cur];

    f32x16 s0 = {}, s1 = {};
    __builtin_amdgcn_s_setprio(1);
#pragma unroll
    for (int kc = 0; kc < 4; ++kc) {
      bf16x8 kf0 = *(const bf16x8*)(Kc + SWZ256(l31 * 128 + kc * 32 + hi * 16));
      s0 = MFMA32(kf0, qfrag[kc], s0);
      bf16x8 kf1 = *(const bf16x8*)(Kc + SWZ256((32 + l31) * 128 + kc * 32 + hi * 16));
      s1 = MFMA32(kf1, qfrag[kc], s1);
    }
    __builtin_amdgcn_s_setprio(0);

    if (j0 + 64 > qw0) {
#pragma unroll
      for (int r = 0; r < 16; ++r) {
        const int k0 = j0 + (r & 3) + 8 * (r >> 2) + 4 * hi;
        if (k0 > qabs)      s0[r] = -3.0e38f;
        if (k0 + 32 > qabs) s1[r] = -3.0e38f;
      }
    }

    bf16x8 pf[4];
    softmax_chunk(s0, s1, o0, o1, mrun, lrun, pf);

    f32x16 lacc = {};
    __builtin_amdgcn_s_setprio(1);
#pragma unroll
    for (int c = 0; c < 4; ++c) {
      bf16x8 vf0 = *(const bf16x8*)(Vc + SWZ256(l31 * 128 + c * 32 + hi * 16));
      o0 = MFMA32(vf0, pf[c], o0);
      bf16x8 vf1 = *(const bf16x8*)(Vc + SWZ256((32 + l31) * 128 + c * 32 + hi * 16));
      o1 = MFMA32(vf1, pf[c], o1);
      lacc = MFMA32(ones, pf[c], lacc);
    }
    __builtin_amdgcn_s_setprio(0);
    lrun += lacc[0];
  }

  const int b = bh >> 4, h = bh & 15;
  const float inv = 1.0f / lrun;
  short* orow = O2 + ((size_t)b * M_ + qabs) * 1024 + h * 64;
#pragma unroll
  for (int vb = 0; vb < 2; ++vb) {
    const f32x16& o = vb ? o1 : o0;
#pragma unroll
    for (int g = 0; g < 4; ++g) {
      const int vbase = vb * 32 + 8 * g + 4 * hi;
      u16x4 pkt;
      pkt[0] = f2b(o[g * 4 + 0] * inv);
      pkt[1] = f2b(o[g * 4 + 1] * inv);
      pkt[2] = f2b(o[g * 4 + 2] * inv);
      pkt[3] = f2b(o[g * 4 + 3] * inv);
      *(u16x4*)(orow + vbase) = pkt;
    }
  }
}

// ---------------------------------------------------------------------------
extern "C" void kernel_launch(void* const* d_in, const int* in_sizes, int n_in,
                              void* d_out, int out_size, void* d_ws, size_t ws_size,
                              hipStream_t stream) {
  const float* x  = (const float*)d_in[0];
  const float* Pq = (const float*)d_in[1];
  const float* Pk = (const float*)d_in[2];
  const float* Pv = (const float*)d_in[3];
  const float* Po = (const float*)d_in[4];
  float* y = (float*)d_out;

  short* ws = (short*)d_ws;
  const size_t NX = (size_t)B_ * M_ * D_;        // 8,388,608
  short* xb  = ws;                 ws += NX;
  short* Wt  = ws;                 ws += (size_t)3072 * 1024;
  short* Wo  = ws;                 ws += (size_t)1024 * 1024;
  short* Qw  = ws;                 ws += NX;
  short* Kw  = ws;                 ws += NX;
  short* Vt  = ws;                 ws += NX;
  short* O2  = ws;                 ws += NX;

  convert_all_kernel<<<8192, 256, 0, stream>>>(x, Pq, Pk, Pv, Po, xb, Wt, Wo);
  qkv_gemm_kernel   <<<1536, 256, 0, stream>>>(xb, Wt, Qw, Kw, Vt);
  attn_kernel       <<<1024, 256, 0, stream>>>(Qw, Kw, Vt, O2);
  out_gemm_kernel   <<<512,  256, 0, stream>>>(O2, Wo, y);
}

// Round 17
// 176.210 us; speedup vs baseline: 1.4058x; 1.0022x over previous
//
#include <hip/hip_runtime.h>
#include <hip/hip_bf16.h>

// B=4, M=2048, D=1024, H=16, K=V=64
#define B_  4
#define M_  2048
#define D_  1024
#define H_  16

typedef __attribute__((ext_vector_type(8)))  short bf16x8;
typedef __attribute__((ext_vector_type(4)))  float f32x4;
typedef __attribute__((ext_vector_type(16))) float f32x16;
typedef __attribute__((ext_vector_type(4)))  unsigned short u16x4;
typedef __attribute__((ext_vector_type(2)))  unsigned int uint2v;

#define MFMA16(a, b, c) __builtin_amdgcn_mfma_f32_16x16x32_bf16((a), (b), (c), 0, 0, 0)
#define MFMA32(a, b, c) __builtin_amdgcn_mfma_f32_32x32x16_bf16((a), (b), (c), 0, 0, 0)

// Q pre-scale: 1/sqrt(64) * log2(e)  (softmax done in exp2 domain)
#define QSCALE 0.18033688011112042f

__device__ __forceinline__ unsigned short f2b(float f) {
  union { float f; unsigned u; } v; v.f = f;
  unsigned r = v.u + 0x7FFF + ((v.u >> 16) & 1);   // RNE
  return (unsigned short)(r >> 16);
}

__device__ __forceinline__ unsigned cvtpk(float lo, float hi) {
  unsigned r;
  asm("v_cvt_pk_bf16_f32 %0, %1, %2" : "=v"(r) : "v"(lo), "v"(hi));
  return r;
}

// GEMM-tile swizzle: 128B rows, XOR 16B-slot bits 4-6 with row low bits.
__device__ __forceinline__ int swzb(int byte) {
  return byte ^ (((byte >> 7) & 7) << 4);
}

// Attention swizzle: 256B macro-rows.
#define SWZ256(L) ((L) ^ ((((L) >> 8) & 15) << 4))

#define GLOAD16(gsrc, ldst)                                                     \
  __builtin_amdgcn_global_load_lds(                                             \
      (const __attribute__((address_space(1))) void*)(gsrc),                    \
      (__attribute__((address_space(3))) void*)(ldst), 16, 0, 0)

// ---------------------------------------------------------------------------
// Fused conversions: one launch. blocks [0,4096): x -> bf16;
// [4096,7168): P_qkv -> Wt[n][d]; [7168,8192): P_o -> Wo[d][hv].
// ---------------------------------------------------------------------------
__global__ __launch_bounds__(256) void convert_all_kernel(
    const float* __restrict__ x,  const float* __restrict__ Pq,
    const float* __restrict__ Pk, const float* __restrict__ Pv,
    const float* __restrict__ Po,
    short* __restrict__ xb, short* __restrict__ Wt, short* __restrict__ Wo) {
  const int bid = blockIdx.x;
  if (bid < 4096) {
    const size_t i = ((size_t)bid * 256 + threadIdx.x) * 8;
    float4 a = *(const float4*)(x + i);
    float4 b = *(const float4*)(x + i + 4);
    bf16x8 o;
    o[0] = (short)f2b(a.x); o[1] = (short)f2b(a.y); o[2] = (short)f2b(a.z); o[3] = (short)f2b(a.w);
    o[4] = (short)f2b(b.x); o[5] = (short)f2b(b.y); o[6] = (short)f2b(b.z); o[7] = (short)f2b(b.w);
    *(bf16x8*)(xb + i) = o;
  } else if (bid < 7168) {
    const int idx = (bid - 4096) * 256 + threadIdx.x;   // n*256 + d/4
    const int n = idx >> 8, d0 = (idx & 255) * 4;
    const int which = n >> 10, h = (n >> 6) & 15, kc = n & 63;
    const float* P = (which == 0) ? Pq : (which == 1) ? Pk : Pv;
    const float* p = P + ((size_t)h * D_ + d0) * 64 + kc;
    u16x4 o;
    o[0] = f2b(p[0]); o[1] = f2b(p[64]); o[2] = f2b(p[128]); o[3] = f2b(p[192]);
    *(u16x4*)(Wt + (size_t)n * D_ + d0) = o;
  } else {
    const int idx = (bid - 7168) * 256 + threadIdx.x;   // d*256 + hv/4
    const int d = idx >> 8, hv0 = (idx & 255) * 4;
    const int h = hv0 >> 6, v = hv0 & 63;
    float4 a = *(const float4*)(Po + ((size_t)h * D_ + d) * 64 + v);
    u16x4 o;
    o[0] = f2b(a.x); o[1] = f2b(a.y); o[2] = f2b(a.z); o[3] = f2b(a.w);
    *(u16x4*)(Wo + (size_t)d * 1024 + hv0) = o;
  }
}

// ---------------------------------------------------------------------------
// Single-buffered m97-style GEMM body (proven): 128x128, BK=64,
// 256 threads, 32 KB LDS -> ~4-5 co-resident blocks/CU (m114 overlap).
// ---------------------------------------------------------------------------
__device__ __forceinline__ void gemm_body_sb(
    const char* __restrict__ Agc, const char* __restrict__ Bgc,
    short* As, short* Bs, int t, int w, int lane,
    f32x4 (&acc)[4][4])
{
  const int wr = (w >> 1) * 64, wc = (w & 1) * 64;
  const int lrow = lane & 15, lgrp = lane >> 4;

  for (int kt = 0; kt < 16; ++kt) {
    __syncthreads();                         // all waves done reading LDS
    const int d2 = kt * 128;                 // K-offset in bytes
#pragma unroll
    for (int i = 0; i < 4; ++i) {            // 128 rows x 128B each side
      const int L = i * 4096 + t * 16;
      const int row = L >> 7;
      const int cs = (L & 127) ^ ((row & 7) << 4);
      GLOAD16(Agc + (size_t)row * 2048 + d2 + cs, (char*)As + L);
      GLOAD16(Bgc + (size_t)row * 2048 + d2 + cs, (char*)Bs + L);
    }
    __syncthreads();                         // drains vmcnt -> tile visible
#pragma unroll
    for (int ks = 0; ks < 2; ++ks) {
      bf16x8 a[4], b[4];
      const int cb = ks * 64 + lgrp * 16;
#pragma unroll
      for (int f = 0; f < 4; ++f) {
        a[f] = *(const bf16x8*)((const char*)As + swzb((wr + f * 16 + lrow) * 128 + cb));
        b[f] = *(const bf16x8*)((const char*)Bs + swzb((wc + f * 16 + lrow) * 128 + cb));
      }
      __builtin_amdgcn_s_setprio(1);
#pragma unroll
      for (int mf = 0; mf < 4; ++mf)
#pragma unroll
        for (int nf = 0; nf < 4; ++nf)
          acc[mf][nf] = MFMA16(a[mf], b[nf], acc[mf][nf]);
      __builtin_amdgcn_s_setprio(0);
    }
  }
}

// ---------------------------------------------------------------------------
// QKV projection GEMM (proven)
// ---------------------------------------------------------------------------
__global__ __launch_bounds__(256) void qkv_gemm_kernel(
    const short* __restrict__ xb, const short* __restrict__ Wt,
    short* __restrict__ Qw, short* __restrict__ Kw, short* __restrict__ Vt) {
  __shared__ short As[8192];
  __shared__ short Bs[8192];
  const int bid = blockIdx.x;                 // 1536
  const int xcd = bid & 7, slot = bid >> 3;   // slot 0..191
  const int m0 = (xcd * 8 + (slot & 7)) * 128;
  const int n0 = (slot >> 3) * 128;
  const int t = threadIdx.x, lane = t & 63, w = t >> 6;

  f32x4 acc[4][4] = {};
  gemm_body_sb((const char*)xb + (size_t)m0 * 2048,
               (const char*)Wt + (size_t)n0 * 2048,
               As, Bs, t, w, lane, acc);

  const int wr = (w >> 1) * 64, wc = (w & 1) * 64;
  const int lrow = lane & 15, lgrp = lane >> 4;
#pragma unroll
  for (int nf = 0; nf < 4; ++nf) {
    const int n = n0 + wc + nf * 16 + lrow;
    const int which = n >> 10, h = (n >> 6) & 15, kc = n & 63;
#pragma unroll
    for (int mf = 0; mf < 4; ++mf) {
      const int row0 = m0 + wr + mf * 16 + lgrp * 4;
      const int b = row0 >> 11, mm = row0 & 2047;
      const int bh = b * 16 + h;
      if (which == 2) {
        u16x4 o;
        o[0] = f2b(acc[mf][nf][0]); o[1] = f2b(acc[mf][nf][1]);
        o[2] = f2b(acc[mf][nf][2]); o[3] = f2b(acc[mf][nf][3]);
        *(u16x4*)(Vt + ((size_t)bh * 64 + kc) * M_ + mm) = o;
      } else {
        short* outp = (which == 0 ? Qw : Kw) + ((size_t)bh * M_ + mm) * 64 + kc;
        const float scale = (which == 0) ? QSCALE : 1.0f;
#pragma unroll
        for (int r = 0; r < 4; ++r)
          outp[(size_t)r * 64] = (short)f2b(acc[mf][nf][r] * scale);
      }
    }
  }
}

// ---------------------------------------------------------------------------
// Output projection (proven)
// ---------------------------------------------------------------------------
__global__ __launch_bounds__(256) void out_gemm_kernel(
    const short* __restrict__ O2, const short* __restrict__ Wo,
    float* __restrict__ y) {
  __shared__ short As[8192];
  __shared__ short Bs[8192];
  const int bid = blockIdx.x;                 // 512
  const int xcd = bid & 7, slot = bid >> 3;   // slot 0..63
  const int m0 = (xcd * 8 + (slot & 7)) * 128;
  const int n0 = (slot >> 3) * 128;
  const int t = threadIdx.x, lane = t & 63, w = t >> 6;

  f32x4 acc[4][4] = {};
  gemm_body_sb((const char*)O2 + (size_t)m0 * 2048,
               (const char*)Wo + (size_t)n0 * 2048,
               As, Bs, t, w, lane, acc);

  const int wr = (w >> 1) * 64, wc = (w & 1) * 64;
  const int lrow = lane & 15, lgrp = lane >> 4;
#pragma unroll
  for (int mf = 0; mf < 4; ++mf)
#pragma unroll
    for (int nf = 0; nf < 4; ++nf) {
      const int n = n0 + wc + nf * 16 + lrow;
      const int row0 = m0 + wr + mf * 16 + lgrp * 4;
#pragma unroll
      for (int r = 0; r < 4; ++r)
        y[(size_t)(row0 + r) * 1024 + n] = acc[mf][nf][r];
    }
}

// ---------------------------------------------------------------------------
// Attention softmax (max3-shaped row-max, T13 defer, T12 cvtpk+permlane)
// ---------------------------------------------------------------------------
__device__ __forceinline__ void softmax_chunk(
    f32x16& s0, f32x16& s1, f32x16& o0, f32x16& o1,
    float& mrun, float& lrun, bf16x8 (&pf)[4])
{
  // row max over 32 values: triples fuse to v_max3_f32
  float a[8];
#pragma unroll
  for (int r = 0; r < 8; ++r)
    a[r] = fmaxf(fmaxf(fmaxf(s0[r], s0[r + 8]), s1[r]), s1[r + 8]);
  float b0 = fmaxf(fmaxf(a[0], a[1]), a[2]);
  float b1 = fmaxf(fmaxf(a[3], a[4]), a[5]);
  float b2 = fmaxf(fmaxf(a[6], a[7]), b0);
  float tmax = fmaxf(b1, b2);
  uint2v pm = __builtin_amdgcn_permlane32_swap(
      __float_as_uint(tmax), __float_as_uint(tmax), false, false);
  const float mtile = fmaxf(__uint_as_float(pm[0]), __uint_as_float(pm[1]));

  // T13 defer-max: skip rescale while max grows < 8 (exp2 domain; P <= 256)
  if (!__all(mtile <= mrun + 8.0f)) {
    const float mnew = fmaxf(mrun, mtile);
    const float alpha = __builtin_amdgcn_exp2f(mrun - mnew);
    mrun = mnew;
    lrun *= alpha;
    o0 *= alpha;
    o1 *= alpha;
  }
#pragma unroll
  for (int r = 0; r < 16; ++r) {
    s0[r] = __builtin_amdgcn_exp2f(s0[r] - mrun);
    s1[r] = __builtin_amdgcn_exp2f(s1[r] - mrun);
  }
  // P -> bf16 PV B-operand frags, fully in-register (T12)
#pragma unroll
  for (int c = 0; c < 4; ++c) {
    const f32x16& sv = (c < 2) ? s0 : s1;    // c is unroll-constant
    const int rb = (c & 1) * 8;
    unsigned a0 = cvtpk(sv[rb + 0], sv[rb + 1]);
    unsigned a1 = cvtpk(sv[rb + 2], sv[rb + 3]);
    unsigned b0_ = cvtpk(sv[rb + 4], sv[rb + 5]);
    unsigned b1_ = cvtpk(sv[rb + 6], sv[rb + 7]);
    uint2v t0 = __builtin_amdgcn_permlane32_swap(a0, b0_, false, false);
    uint2v t1 = __builtin_amdgcn_permlane32_swap(a1, b1_, false, false);
    union { unsigned u[4]; bf16x8 v; } pk;
    pk.u[0] = t0[0]; pk.u[1] = t1[0]; pk.u[2] = t0[1]; pk.u[3] = t1[1];
    pf[c] = pk.v;
  }
}

// ---------------------------------------------------------------------------
// Flash attention (proven): 1024 blocks = 16 chunks (heavy-first) x
// 64 bh; dbuf LDS + counted vmcnt(4); VGPR ~92 -> 5 blocks/CU.
// ---------------------------------------------------------------------------
__global__ __launch_bounds__(256) void attn_kernel(
    const short* __restrict__ Qw, const short* __restrict__ Kw,
    const short* __restrict__ Vt, short* __restrict__ O2) {
  __shared__ short Ks[2][64 * 64];
  __shared__ short Vs[2][64 * 64];

  const int bid = blockIdx.x;                 // 1024 blocks
  const int chunk = 15 - (bid >> 6);          // heavy-first
  const int bh = bid & 63;                    // bh%8 == dispatch XCD
  const int q0 = chunk * 128;

  const int t = threadIdx.x, lane = t & 63, w = t >> 6;
  const int l31 = lane & 31, hi = lane >> 5;
  const int qw0 = q0 + w * 32;
  const int qabs = qw0 + l31;

  bf16x8 qfrag[4];
#pragma unroll
  for (int kc = 0; kc < 4; ++kc)
    qfrag[kc] = *(const bf16x8*)(Qw + ((size_t)bh * M_ + qabs) * 64 + kc * 16 + hi * 8);

  f32x16 o0 = {}, o1 = {};
  float mrun = -3.0e38f, lrun = 0.f;

  const char* Kg = (const char*)Kw + (size_t)bh * M_ * 128;
  const char* Vg = (const char*)Vt + (size_t)bh * 64 * M_ * 2;

  auto stage = [&](int bi, int j0_) {
#pragma unroll
    for (int i = 0; i < 2; ++i) {
      const int L  = i * 4096 + t * 16;
      const int Ls = SWZ256(L);
      const int row = Ls >> 7, col = Ls & 127;
      GLOAD16(Kg + (size_t)(j0_ + row) * 128 + col, (char*)Ks[bi] + i * 4096 + w * 1024);
      GLOAD16(Vg + (size_t)row * (M_ * 2) + (size_t)j0_ * 2 + col, (char*)Vs[bi] + i * 4096 + w * 1024);
    }
  };

  const int nt = (q0 + 128) >> 6;
  stage(0, 0);

  bf16x8 ones;
#pragma unroll
  for (int e = 0; e < 8; ++e) ones[e] = (short)0x3F80;

  for (int tt = 0; tt < nt; ++tt) {
    const int j0 = tt << 6;
    const int cur = tt & 1;
    __builtin_amdgcn_s_barrier();
    if (tt + 1 < nt) {
      stage(cur ^ 1, j0 + 64);
      asm volatile("s_waitcnt vmcnt(4)" ::: "memory");
    } else {
      asm volatile("s_waitcnt vmcnt(0)" ::: "memory");
    }
    __builtin_amdgcn_s_barrier();
    if (j0 >= qw0 + 32) continue;

    const char* Kc = (const char*)Ks[cur];
    const char* Vc = (const char*)Vs[cur];

    f32x16 s0 = {}, s1 = {};
    __builtin_amdgcn_s_setprio(1);
#pragma unroll
    for (int kc = 0; kc < 4; ++kc) {
      bf16x8 kf0 = *(const bf16x8*)(Kc + SWZ256(l31 * 128 + kc * 32 + hi * 16));
      s0 = MFMA32(kf0, qfrag[kc], s0);
      bf16x8 kf1 = *(const bf16x8*)(Kc + SWZ256((32 + l31) * 128 + kc * 32 + hi * 16));
      s1 = MFMA32(kf1, qfrag[kc], s1);
    }
    __builtin_amdgcn_s_setprio(0);

    if (j0 + 64 > qw0) {
#pragma unroll
      for (int r = 0; r < 16; ++r) {
        const int k0 = j0 + (r & 3) + 8 * (r >> 2) + 4 * hi;
        if (k0 > qabs)      s0[r] = -3.0e38f;
        if (k0 + 32 > qabs) s1[r] = -3.0e38f;
      }
    }

    bf16x8 pf[4];
    softmax_chunk(s0, s1, o0, o1, mrun, lrun, pf);

    f32x16 lacc = {};
    __builtin_amdgcn_s_setprio(1);
#pragma unroll
    for (int c = 0; c < 4; ++c) {
      bf16x8 vf0 = *(const bf16x8*)(Vc + SWZ256(l31 * 128 + c * 32 + hi * 16));
      o0 = MFMA32(vf0, pf[c], o0);
      bf16x8 vf1 = *(const bf16x8*)(Vc + SWZ256((32 + l31) * 128 + c * 32 + hi * 16));
      o1 = MFMA32(vf1, pf[c], o1);
      lacc = MFMA32(ones, pf[c], lacc);
    }
    __builtin_amdgcn_s_setprio(0);
    lrun += lacc[0];
  }

  const int b = bh >> 4, h = bh & 15;
  const float inv = 1.0f / lrun;
  short* orow = O2 + ((size_t)b * M_ + qabs) * 1024 + h * 64;
#pragma unroll
  for (int vb = 0; vb < 2; ++vb) {
    const f32x16& o = vb ? o1 : o0;
#pragma unroll
    for (int g = 0; g < 4; ++g) {
      const int vbase = vb * 32 + 8 * g + 4 * hi;
      u16x4 pkt;
      pkt[0] = f2b(o[g * 4 + 0] * inv);
      pkt[1] = f2b(o[g * 4 + 1] * inv);
      pkt[2] = f2b(o[g * 4 + 2] * inv);
      pkt[3] = f2b(o[g * 4 + 3] * inv);
      *(u16x4*)(orow + vbase) = pkt;
    }
  }
}

// ---------------------------------------------------------------------------
extern "C" void kernel_launch(void* const* d_in, const int* in_sizes, int n_in,
                              void* d_out, int out_size, void* d_ws, size_t ws_size,
                              hipStream_t stream) {
  const float* x  = (const float*)d_in[0];
  const float* Pq = (const float*)d_in[1];
  const float* Pk = (const float*)d_in[2];
  const float* Pv = (const float*)d_in[3];
  const float* Po = (const float*)d_in[4];
  float* y = (float*)d_out;

  short* ws = (short*)d_ws;
  const size_t NX = (size_t)B_ * M_ * D_;        // 8,388,608
  short* xb  = ws;                 ws += NX;
  short* Wt  = ws;                 ws += (size_t)3072 * 1024;
  short* Wo  = ws;                 ws += (size_t)1024 * 1024;
  short* Qw  = ws;                 ws += NX;
  short* Kw  = ws;                 ws += NX;
  short* Vt  = ws;                 ws += NX;
  short* O2  = ws;                 ws += NX;

  convert_all_kernel<<<8192, 256, 0, stream>>>(x, Pq, Pk, Pv, Po, xb, Wt, Wo);
  qkv_gemm_kernel   <<<1536, 256, 0, stream>>>(xb, Wt, Qw, Kw, Vt);
  attn_kernel       <<<1024, 256, 0, stream>>>(Qw, Kw, Vt, O2);
  out_gemm_kernel   <<<512,  256, 0, stream>>>(O2, Wo, y);
}

// Round 18
// 175.488 us; speedup vs baseline: 1.4115x; 1.0041x over previous
//
#include <hip/hip_runtime.h>
#include <hip/hip_bf16.h>

// B=4, M=2048, D=1024, H=16, K=V=64
#define B_  4
#define M_  2048
#define D_  1024
#define H_  16

typedef __attribute__((ext_vector_type(8)))  short bf16x8;
typedef __attribute__((ext_vector_type(4)))  float f32x4;
typedef __attribute__((ext_vector_type(16))) float f32x16;
typedef __attribute__((ext_vector_type(4)))  unsigned short u16x4;
typedef __attribute__((ext_vector_type(2)))  unsigned int uint2v;

#define MFMA16(a, b, c) __builtin_amdgcn_mfma_f32_16x16x32_bf16((a), (b), (c), 0, 0, 0)
#define MFMA32(a, b, c) __builtin_amdgcn_mfma_f32_32x32x16_bf16((a), (b), (c), 0, 0, 0)

// Q pre-scale: 1/sqrt(64) * log2(e)  (softmax done in exp2 domain)
#define QSCALE 0.18033688011112042f

__device__ __forceinline__ unsigned short f2b(float f) {
  union { float f; unsigned u; } v; v.f = f;
  unsigned r = v.u + 0x7FFF + ((v.u >> 16) & 1);   // RNE
  return (unsigned short)(r >> 16);
}

__device__ __forceinline__ unsigned cvtpk(float lo, float hi) {
  unsigned r;
  asm("v_cvt_pk_bf16_f32 %0, %1, %2" : "=v"(r) : "v"(lo), "v"(hi));
  return r;
}

// GEMM-tile swizzle: 128B rows, XOR 16B-slot bits 4-6 with row low bits.
__device__ __forceinline__ int swzb(int byte) {
  return byte ^ (((byte >> 7) & 7) << 4);
}

// Attention swizzle: 256B macro-rows, XOR slot bits 4-7 with bits 8-11.
#define SWZ256(L) ((L) ^ ((((L) >> 8) & 15) << 4))

#define GLOAD16(gsrc, ldst)                                                     \
  __builtin_amdgcn_global_load_lds(                                             \
      (const __attribute__((address_space(1))) void*)(gsrc),                    \
      (__attribute__((address_space(3))) void*)(ldst), 16, 0, 0)

// ---------------------------------------------------------------------------
// Fused conversions (proven): one launch. blocks [0,4096): x -> bf16;
// [4096,7168): P_qkv -> Wt[n][d]; [7168,8192): P_o -> Wo[d][hv].
// ---------------------------------------------------------------------------
__global__ __launch_bounds__(256) void convert_all_kernel(
    const float* __restrict__ x,  const float* __restrict__ Pq,
    const float* __restrict__ Pk, const float* __restrict__ Pv,
    const float* __restrict__ Po,
    short* __restrict__ xb, short* __restrict__ Wt, short* __restrict__ Wo) {
  const int bid = blockIdx.x;
  if (bid < 4096) {
    const size_t i = ((size_t)bid * 256 + threadIdx.x) * 8;
    float4 a = *(const float4*)(x + i);
    float4 b = *(const float4*)(x + i + 4);
    bf16x8 o;
    o[0] = (short)f2b(a.x); o[1] = (short)f2b(a.y); o[2] = (short)f2b(a.z); o[3] = (short)f2b(a.w);
    o[4] = (short)f2b(b.x); o[5] = (short)f2b(b.y); o[6] = (short)f2b(b.z); o[7] = (short)f2b(b.w);
    *(bf16x8*)(xb + i) = o;
  } else if (bid < 7168) {
    const int idx = (bid - 4096) * 256 + threadIdx.x;   // n*256 + d/4
    const int n = idx >> 8, d0 = (idx & 255) * 4;
    const int which = n >> 10, h = (n >> 6) & 15, kc = n & 63;
    const float* P = (which == 0) ? Pq : (which == 1) ? Pk : Pv;
    const float* p = P + ((size_t)h * D_ + d0) * 64 + kc;
    u16x4 o;
    o[0] = f2b(p[0]); o[1] = f2b(p[64]); o[2] = f2b(p[128]); o[3] = f2b(p[192]);
    *(u16x4*)(Wt + (size_t)n * D_ + d0) = o;
  } else {
    const int idx = (bid - 7168) * 256 + threadIdx.x;   // d*256 + hv/4
    const int d = idx >> 8, hv0 = (idx & 255) * 4;
    const int h = hv0 >> 6, v = hv0 & 63;
    float4 a = *(const float4*)(Po + ((size_t)h * D_ + d) * 64 + v);
    u16x4 o;
    o[0] = f2b(a.x); o[1] = f2b(a.y); o[2] = f2b(a.z); o[3] = f2b(a.w);
    *(u16x4*)(Wo + (size_t)d * 1024 + hv0) = o;
  }
}

// ---------------------------------------------------------------------------
// Single-buffered m97-style GEMM body (proven): 128x128, BK=64,
// 256 threads, 32 KB LDS -> ~4-5 co-resident blocks/CU (m114 overlap).
// ---------------------------------------------------------------------------
__device__ __forceinline__ void gemm_body_sb(
    const char* __restrict__ Agc, const char* __restrict__ Bgc,
    short* As, short* Bs, int t, int w, int lane,
    f32x4 (&acc)[4][4])
{
  const int wr = (w >> 1) * 64, wc = (w & 1) * 64;
  const int lrow = lane & 15, lgrp = lane >> 4;

  for (int kt = 0; kt < 16; ++kt) {
    __syncthreads();                         // all waves done reading LDS
    const int d2 = kt * 128;                 // K-offset in bytes
#pragma unroll
    for (int i = 0; i < 4; ++i) {            // 128 rows x 128B each side
      const int L = i * 4096 + t * 16;
      const int row = L >> 7;
      const int cs = (L & 127) ^ ((row & 7) << 4);
      GLOAD16(Agc + (size_t)row * 2048 + d2 + cs, (char*)As + L);
      GLOAD16(Bgc + (size_t)row * 2048 + d2 + cs, (char*)Bs + L);
    }
    __syncthreads();                         // drains vmcnt -> tile visible
#pragma unroll
    for (int ks = 0; ks < 2; ++ks) {
      bf16x8 a[4], b[4];
      const int cb = ks * 64 + lgrp * 16;
#pragma unroll
      for (int f = 0; f < 4; ++f) {
        a[f] = *(const bf16x8*)((const char*)As + swzb((wr + f * 16 + lrow) * 128 + cb));
        b[f] = *(const bf16x8*)((const char*)Bs + swzb((wc + f * 16 + lrow) * 128 + cb));
      }
      __builtin_amdgcn_s_setprio(1);
#pragma unroll
      for (int mf = 0; mf < 4; ++mf)
#pragma unroll
        for (int nf = 0; nf < 4; ++nf)
          acc[mf][nf] = MFMA16(a[mf], b[nf], acc[mf][nf]);
      __builtin_amdgcn_s_setprio(0);
    }
  }
}

// ---------------------------------------------------------------------------
// QKV projection GEMM (proven)
// ---------------------------------------------------------------------------
__global__ __launch_bounds__(256) void qkv_gemm_kernel(
    const short* __restrict__ xb, const short* __restrict__ Wt,
    short* __restrict__ Qw, short* __restrict__ Kw, short* __restrict__ Vt) {
  __shared__ short As[8192];
  __shared__ short Bs[8192];
  const int bid = blockIdx.x;                 // 1536
  const int xcd = bid & 7, slot = bid >> 3;   // slot 0..191
  const int m0 = (xcd * 8 + (slot & 7)) * 128;
  const int n0 = (slot >> 3) * 128;
  const int t = threadIdx.x, lane = t & 63, w = t >> 6;

  f32x4 acc[4][4] = {};
  gemm_body_sb((const char*)xb + (size_t)m0 * 2048,
               (const char*)Wt + (size_t)n0 * 2048,
               As, Bs, t, w, lane, acc);

  const int wr = (w >> 1) * 64, wc = (w & 1) * 64;
  const int lrow = lane & 15, lgrp = lane >> 4;
#pragma unroll
  for (int nf = 0; nf < 4; ++nf) {
    const int n = n0 + wc + nf * 16 + lrow;
    const int which = n >> 10, h = (n >> 6) & 15, kc = n & 63;
#pragma unroll
    for (int mf = 0; mf < 4; ++mf) {
      const int row0 = m0 + wr + mf * 16 + lgrp * 4;
      const int b = row0 >> 11, mm = row0 & 2047;
      const int bh = b * 16 + h;
      if (which == 2) {
        u16x4 o;
        o[0] = f2b(acc[mf][nf][0]); o[1] = f2b(acc[mf][nf][1]);
        o[2] = f2b(acc[mf][nf][2]); o[3] = f2b(acc[mf][nf][3]);
        *(u16x4*)(Vt + ((size_t)bh * 64 + kc) * M_ + mm) = o;
      } else {
        short* outp = (which == 0 ? Qw : Kw) + ((size_t)bh * M_ + mm) * 64 + kc;
        const float scale = (which == 0) ? QSCALE : 1.0f;
#pragma unroll
        for (int r = 0; r < 4; ++r)
          outp[(size_t)r * 64] = (short)f2b(acc[mf][nf][r] * scale);
      }
    }
  }
}

// ---------------------------------------------------------------------------
// Output projection (proven)
// ---------------------------------------------------------------------------
__global__ __launch_bounds__(256) void out_gemm_kernel(
    const short* __restrict__ O2, const short* __restrict__ Wo,
    float* __restrict__ y) {
  __shared__ short As[8192];
  __shared__ short Bs[8192];
  const int bid = blockIdx.x;                 // 512
  const int xcd = bid & 7, slot = bid >> 3;   // slot 0..63
  const int m0 = (xcd * 8 + (slot & 7)) * 128;
  const int n0 = (slot >> 3) * 128;
  const int t = threadIdx.x, lane = t & 63, w = t >> 6;

  f32x4 acc[4][4] = {};
  gemm_body_sb((const char*)O2 + (size_t)m0 * 2048,
               (const char*)Wo + (size_t)n0 * 2048,
               As, Bs, t, w, lane, acc);

  const int wr = (w >> 1) * 64, wc = (w & 1) * 64;
  const int lrow = lane & 15, lgrp = lane >> 4;
#pragma unroll
  for (int mf = 0; mf < 4; ++mf)
#pragma unroll
    for (int nf = 0; nf < 4; ++nf) {
      const int n = n0 + wc + nf * 16 + lrow;
      const int row0 = m0 + wr + mf * 16 + lgrp * 4;
#pragma unroll
      for (int r = 0; r < 4; ++r)
        y[(size_t)(row0 + r) * 1024 + n] = acc[mf][nf][r];
    }
}

// ---------------------------------------------------------------------------
// Attention softmax (proven: max3-shaped row-max, T13 defer, T12 cvtpk)
// ---------------------------------------------------------------------------
__device__ __forceinline__ void softmax_chunk(
    f32x16& s0, f32x16& s1, f32x16& o0, f32x16& o1,
    float& mrun, float& lrun, bf16x8 (&pf)[4])
{
  // row max over 32 values: triples fuse to v_max3_f32
  float a[8];
#pragma unroll
  for (int r = 0; r < 8; ++r)
    a[r] = fmaxf(fmaxf(fmaxf(s0[r], s0[r + 8]), s1[r]), s1[r + 8]);
  float b0 = fmaxf(fmaxf(a[0], a[1]), a[2]);
  float b1 = fmaxf(fmaxf(a[3], a[4]), a[5]);
  float b2 = fmaxf(fmaxf(a[6], a[7]), b0);
  float tmax = fmaxf(b1, b2);
  uint2v pm = __builtin_amdgcn_permlane32_swap(
      __float_as_uint(tmax), __float_as_uint(tmax), false, false);
  const float mtile = fmaxf(__uint_as_float(pm[0]), __uint_as_float(pm[1]));

  // T13 defer-max: skip rescale while max grows < 8 (exp2 domain; P <= 256)
  if (!__all(mtile <= mrun + 8.0f)) {
    const float mnew = fmaxf(mrun, mtile);
    const float alpha = __builtin_amdgcn_exp2f(mrun - mnew);
    mrun = mnew;
    lrun *= alpha;
    o0 *= alpha;
    o1 *= alpha;
  }
#pragma unroll
  for (int r = 0; r < 16; ++r) {
    s0[r] = __builtin_amdgcn_exp2f(s0[r] - mrun);
    s1[r] = __builtin_amdgcn_exp2f(s1[r] - mrun);
  }
  // P -> bf16 PV B-operand frags, fully in-register (T12)
#pragma unroll
  for (int c = 0; c < 4; ++c) {
    const f32x16& sv = (c < 2) ? s0 : s1;    // c is unroll-constant
    const int rb = (c & 1) * 8;
    unsigned a0 = cvtpk(sv[rb + 0], sv[rb + 1]);
    unsigned a1 = cvtpk(sv[rb + 2], sv[rb + 3]);
    unsigned b0_ = cvtpk(sv[rb + 4], sv[rb + 5]);
    unsigned b1_ = cvtpk(sv[rb + 6], sv[rb + 7]);
    uint2v t0 = __builtin_amdgcn_permlane32_swap(a0, b0_, false, false);
    uint2v t1 = __builtin_amdgcn_permlane32_swap(a1, b1_, false, false);
    union { unsigned u[4]; bf16x8 v; } pk;
    pk.u[0] = t0[0]; pk.u[1] = t1[0]; pk.u[2] = t0[1]; pk.u[3] = t1[1];
    pf[c] = pk.v;
  }
}

// ---------------------------------------------------------------------------
// Flash attention, single-buffered KVBLK=128: Ks[128x64] + Vs[64x128] =
// 32 KB (same as prior dbuf-64 -> still 5 blocks/CU), but HALF the barriers:
// per 128 keys {sync -> stage 8 GLOAD16 -> sync -> 2 compute sub-tiles}.
// Prefetch loss is covered by 5-block co-residency (m97/m114 — the GEMM
// A/B r8 vs r10 showed sb+occupancy >= dbuf at >=4 blocks/CU).
// 1024 blocks = 16 chunks (heavy-first) x 64 bh; bh%8 pins XCD.
// ---------------------------------------------------------------------------
__global__ __launch_bounds__(256) void attn_kernel(
    const short* __restrict__ Qw, const short* __restrict__ Kw,
    const short* __restrict__ Vt, short* __restrict__ O2) {
  __shared__ short Ks[128 * 64];   // 16 KB: 128 key-rows x 64 elems (128B rows)
  __shared__ short Vs[64 * 128];   // 16 KB: 64 v-rows x 128 keys   (256B rows)

  const int bid = blockIdx.x;                 // 1024 blocks
  const int chunk = 15 - (bid >> 6);          // heavy-first
  const int bh = bid & 63;                    // bh%8 == dispatch XCD
  const int q0 = chunk * 128;

  const int t = threadIdx.x, lane = t & 63, w = t >> 6;
  const int l31 = lane & 31, hi = lane >> 5;
  const int qw0 = q0 + w * 32;
  const int qabs = qw0 + l31;

  bf16x8 qfrag[4];
#pragma unroll
  for (int kc = 0; kc < 4; ++kc)
    qfrag[kc] = *(const bf16x8*)(Qw + ((size_t)bh * M_ + qabs) * 64 + kc * 16 + hi * 8);

  f32x16 o0 = {}, o1 = {};
  float mrun = -3.0e38f, lrun = 0.f;

  const char* Kg = (const char*)Kw + (size_t)bh * M_ * 128;
  const char* Vg = (const char*)Vt + (size_t)bh * 64 * (M_ * 2);

  bf16x8 ones;
#pragma unroll
  for (int e = 0; e < 8; ++e) ones[e] = (short)0x3F80;

  const int nIter = chunk + 1;                // ceil((q0+128)/128)
  for (int it = 0; it < nIter; ++it) {
    const int j128 = it << 7;
    __syncthreads();                          // all waves done reading LDS
    // stage K tile: [128 rows][64 elems], linear dest, swizzled source
#pragma unroll
    for (int i = 0; i < 4; ++i) {
      const int L  = i * 4096 + t * 16;
      const int Ls = SWZ256(L);
      const int row = Ls >> 7, col = Ls & 127;
      GLOAD16(Kg + (size_t)(j128 + row) * 128 + col, (char*)Ks + i * 4096 + w * 1024);
    }
    // stage V tile: [64 v-rows][128 keys x 2B = 256B rows]
#pragma unroll
    for (int i = 0; i < 4; ++i) {
      const int L  = i * 4096 + t * 16;
      const int Ls = SWZ256(L);
      const int row = Ls >> 8, col = Ls & 255;
      GLOAD16(Vg + (size_t)row * (M_ * 2) + (size_t)j128 * 2 + col, (char*)Vs + i * 4096 + w * 1024);
    }
    __syncthreads();                          // drains vmcnt -> tiles visible

#pragma unroll
    for (int sub = 0; sub < 2; ++sub) {
      const int j0 = j128 + sub * 64;
      if (j0 >= qw0 + 32) continue;           // beyond this wave's causal bound

      // ---- S^T = K . Q^T ----
      f32x16 s0 = {}, s1 = {};
      __builtin_amdgcn_s_setprio(1);
#pragma unroll
      for (int kc = 0; kc < 4; ++kc) {
        bf16x8 kf0 = *(const bf16x8*)((const char*)Ks +
                       SWZ256((sub * 64 + l31) * 128 + kc * 32 + hi * 16));
        s0 = MFMA32(kf0, qfrag[kc], s0);
        bf16x8 kf1 = *(const bf16x8*)((const char*)Ks +
                       SWZ256((sub * 64 + 32 + l31) * 128 + kc * 32 + hi * 16));
        s1 = MFMA32(kf1, qfrag[kc], s1);
      }
      __builtin_amdgcn_s_setprio(0);

      // ---- causal mask (diagonal tiles only) ----
      if (j0 + 64 > qw0) {
#pragma unroll
        for (int r = 0; r < 16; ++r) {
          const int k0 = j0 + (r & 3) + 8 * (r >> 2) + 4 * hi;
          if (k0 > qabs)      s0[r] = -3.0e38f;
          if (k0 + 32 > qabs) s1[r] = -3.0e38f;
        }
      }

      // ---- online softmax + P->bf16 frags ----
      bf16x8 pf[4];
      softmax_chunk(s0, s1, o0, o1, mrun, lrun, pf);

      // ---- O^T += V^T . P + rowsum on MFMA pipe ----
      f32x16 lacc = {};
      __builtin_amdgcn_s_setprio(1);
#pragma unroll
      for (int c = 0; c < 4; ++c) {
        bf16x8 vf0 = *(const bf16x8*)((const char*)Vs +
                       SWZ256(l31 * 256 + sub * 128 + c * 32 + hi * 16));
        o0 = MFMA32(vf0, pf[c], o0);
        bf16x8 vf1 = *(const bf16x8*)((const char*)Vs +
                       SWZ256((32 + l31) * 256 + sub * 128 + c * 32 + hi * 16));
        o1 = MFMA32(vf1, pf[c], o1);
        lacc = MFMA32(ones, pf[c], lacc);
      }
      __builtin_amdgcn_s_setprio(0);
      lrun += lacc[0];
    }
  }

  // ---- epilogue: O2[b][m=qabs][h*64 + v] = O^T / l ----
  const int b = bh >> 4, h = bh & 15;
  const float inv = 1.0f / lrun;
  short* orow = O2 + ((size_t)b * M_ + qabs) * 1024 + h * 64;
#pragma unroll
  for (int vb = 0; vb < 2; ++vb) {
    const f32x16& o = vb ? o1 : o0;
#pragma unroll
    for (int g = 0; g < 4; ++g) {
      const int vbase = vb * 32 + 8 * g + 4 * hi;
      u16x4 pkt;
      pkt[0] = f2b(o[g * 4 + 0] * inv);
      pkt[1] = f2b(o[g * 4 + 1] * inv);
      pkt[2] = f2b(o[g * 4 + 2] * inv);
      pkt[3] = f2b(o[g * 4 + 3] * inv);
      *(u16x4*)(orow + vbase) = pkt;
    }
  }
}

// ---------------------------------------------------------------------------
extern "C" void kernel_launch(void* const* d_in, const int* in_sizes, int n_in,
                              void* d_out, int out_size, void* d_ws, size_t ws_size,
                              hipStream_t stream) {
  const float* x  = (const float*)d_in[0];
  const float* Pq = (const float*)d_in[1];
  const float* Pk = (const float*)d_in[2];
  const float* Pv = (const float*)d_in[3];
  const float* Po = (const float*)d_in[4];
  float* y = (float*)d_out;

  short* ws = (short*)d_ws;
  const size_t NX = (size_t)B_ * M_ * D_;        // 8,388,608
  short* xb  = ws;                 ws += NX;
  short* Wt  = ws;                 ws += (size_t)3072 * 1024;
  short* Wo  = ws;                 ws += (size_t)1024 * 1024;
  short* Qw  = ws;                 ws += NX;
  short* Kw  = ws;                 ws += NX;
  short* Vt  = ws;                 ws += NX;
  short* O2  = ws;                 ws += NX;

  convert_all_kernel<<<8192, 256, 0, stream>>>(x, Pq, Pk, Pv, Po, xb, Wt, Wo);
  qkv_gemm_kernel   <<<1536, 256, 0, stream>>>(xb, Wt, Qw, Kw, Vt);
  attn_kernel       <<<1024, 256, 0, stream>>>(Qw, Kw, Vt, O2);
  out_gemm_kernel   <<<512,  256, 0, stream>>>(O2, Wo, y);
}